// Round 1
// baseline (921.200 us; speedup 1.0000x reference)
//
#include <hip/hip_runtime.h>
#include <hip/hip_bf16.h>

typedef __bf16 bf16x8 __attribute__((ext_vector_type(8)));
typedef float f32x4 __attribute__((ext_vector_type(4)));
typedef unsigned short u16;
typedef u16 u16x4 __attribute__((ext_vector_type(4)));

__device__ __forceinline__ u16 f2bf(float f) {
  unsigned u = __builtin_bit_cast(unsigned, f);
  u += 0x7FFFu + ((u >> 16) & 1u);
  return (u16)(u >> 16);
}

// ---------------- prep: weights -> bf16, bias gather ----------------
__global__ void wattn_prep(const float* __restrict__ wq, const float* __restrict__ wp,
                           const float* __restrict__ rpb, const int* __restrict__ rpi,
                           u16* __restrict__ wqb, u16* __restrict__ wpb,
                           float* __restrict__ biasb) {
  int i = blockIdx.x * blockDim.x + threadIdx.x;      // 196608 threads
  if (i < 196608) wqb[i] = f2bf(wq[i]);               // w_qkv [768][256]
  if (i < 65536)  wpb[i] = f2bf(wp[i]);               // w_proj [256][256]
  if (i < 32768) {                                    // bias [8][64][64]
    int h = i >> 12, nm = i & 4095;
    biasb[i] = rpb[rpi[nm] * 8 + h];
  }
}

// ---------------- fused window attention ----------------
// block = 1 window, 512 threads = 8 waves, wave w = head w
// LDS: Xb [64][264] bf16 | QK: 8 x [64][72] bf16 (Q cols0..31,K cols32..63 -> P -> attn_out) | Vt [256][72]
__global__ __launch_bounds__(512, 2)
void wattn_main(const float* __restrict__ x,
                const u16* __restrict__ wq, const float* __restrict__ bq,
                const u16* __restrict__ wp, const float* __restrict__ bp,
                const float* __restrict__ bias,
                float* __restrict__ out) {
  extern __shared__ u16 sm[];
  u16* Xb = sm;                       // 64*264 = 16896
  u16* QK = sm + 16896;               // 8*4608 = 36864
  u16* Vt = QK + 36864;               // 256*72 = 18432

  const int b    = blockIdx.x;
  const int tid  = threadIdx.x;
  const int w    = tid >> 6;          // wave = head
  const int lane = tid & 63;
  const int g    = lane >> 4;
  const int li   = lane & 15;

  // ---- stage x -> bf16 LDS ----
  {
    const float4* xg = (const float4*)(x + (size_t)b * 16384);
    #pragma unroll
    for (int i = 0; i < 8; ++i) {
      int idx = tid + i * 512;        // 0..4095 float4s
      float4 v = xg[idx];
      int n = idx >> 6, c = (idx & 63) * 4;
      u16x4 h; h[0] = f2bf(v.x); h[1] = f2bf(v.y); h[2] = f2bf(v.z); h[3] = f2bf(v.w);
      *(u16x4*)(Xb + n * 264 + c) = h;
    }
  }
  __syncthreads();

  const int hc = 32 * w;              // head col base
  // ---- QKV GEMM: M=64, N=96 (Q|K|V 32 cols each), K=256 ----
  f32x4 acc[6][4];
  #pragma unroll
  for (int i = 0; i < 6; ++i)
    #pragma unroll
    for (int r = 0; r < 4; ++r) acc[i][r] = f32x4{0.f, 0.f, 0.f, 0.f};

  #pragma unroll
  for (int ks = 0; ks < 8; ++ks) {
    bf16x8 a[4];
    #pragma unroll
    for (int rt = 0; rt < 4; ++rt)
      a[rt] = *(const bf16x8*)(Xb + (16 * rt + li) * 264 + 32 * ks + 8 * g);
    #pragma unroll
    for (int pc = 0; pc < 6; ++pc) {
      int p = pc >> 1, ct = pc & 1;
      int row = 256 * p + hc + 16 * ct + li;
      bf16x8 bfr = *(const bf16x8*)(wq + row * 256 + 32 * ks + 8 * g);
      #pragma unroll
      for (int rt = 0; rt < 4; ++rt)
        acc[pc][rt] = __builtin_amdgcn_mfma_f32_16x16x32_bf16(a[rt], bfr, acc[pc][rt], 0, 0, 0);
    }
  }

  u16* R = QK + w * 4608;
  const float scale = 0.17677669529663687f;   // 1/sqrt(32)
  // Q (scaled) -> R cols 0..31, K -> R cols 32..63
  #pragma unroll
  for (int pc = 0; pc < 4; ++pc) {
    int p = pc >> 1, ct = pc & 1;
    int d = 16 * ct + li;
    float bb = bq[256 * p + hc + d];
    #pragma unroll
    for (int rt = 0; rt < 4; ++rt)
      #pragma unroll
      for (int e = 0; e < 4; ++e) {
        float v = acc[pc][rt][e] + bb;
        if (p == 0) v *= scale;
        R[(16 * rt + 4 * g + e) * 72 + 32 * p + d] = f2bf(v);
      }
  }
  // V -> Vt transposed: Vt[32w+d][m]
  #pragma unroll
  for (int ct = 0; ct < 2; ++ct) {
    int d = 16 * ct + li;
    float bb = bq[512 + hc + d];
    #pragma unroll
    for (int rt = 0; rt < 4; ++rt) {
      u16x4 h;
      #pragma unroll
      for (int e = 0; e < 4; ++e) h[e] = f2bf(acc[4 + ct][rt][e] + bb);
      *(u16x4*)(Vt + (32 * w + d) * 72 + 16 * rt + 4 * g) = h;
    }
  }

  // ---- S = Q K^T (64x64, K=32) ----
  f32x4 s[4][4];
  #pragma unroll
  for (int rt = 0; rt < 4; ++rt)
    #pragma unroll
    for (int ct = 0; ct < 4; ++ct) s[rt][ct] = f32x4{0.f, 0.f, 0.f, 0.f};
  {
    bf16x8 qa[4], kb[4];
    #pragma unroll
    for (int rt = 0; rt < 4; ++rt) qa[rt] = *(const bf16x8*)(R + (16 * rt + li) * 72 + 8 * g);
    #pragma unroll
    for (int ct = 0; ct < 4; ++ct) kb[ct] = *(const bf16x8*)(R + (16 * ct + li) * 72 + 32 + 8 * g);
    #pragma unroll
    for (int rt = 0; rt < 4; ++rt)
      #pragma unroll
      for (int ct = 0; ct < 4; ++ct)
        s[rt][ct] = __builtin_amdgcn_mfma_f32_16x16x32_bf16(qa[rt], kb[ct], s[rt][ct], 0, 0, 0);
  }

  // ---- bias + softmax (rows) ; P bf16 -> R cols 0..63 ----
  {
    const float* bh = bias + w * 4096;
    #pragma unroll
    for (int rt = 0; rt < 4; ++rt)
      #pragma unroll
      for (int e = 0; e < 4; ++e) {
        int row = 16 * rt + 4 * g + e;
        float mx = -1e30f;
        #pragma unroll
        for (int ct = 0; ct < 4; ++ct) {
          s[rt][ct][e] += bh[row * 64 + 16 * ct + li];
          mx = fmaxf(mx, s[rt][ct][e]);
        }
        mx = fmaxf(mx, __shfl_xor(mx, 1));
        mx = fmaxf(mx, __shfl_xor(mx, 2));
        mx = fmaxf(mx, __shfl_xor(mx, 4));
        mx = fmaxf(mx, __shfl_xor(mx, 8));
        float sum = 0.f;
        #pragma unroll
        for (int ct = 0; ct < 4; ++ct) {
          float pv = __expf(s[rt][ct][e] - mx);
          s[rt][ct][e] = pv;
          sum += pv;
        }
        sum += __shfl_xor(sum, 1);
        sum += __shfl_xor(sum, 2);
        sum += __shfl_xor(sum, 4);
        sum += __shfl_xor(sum, 8);
        float rs = 1.0f / sum;
        #pragma unroll
        for (int ct = 0; ct < 4; ++ct)
          R[row * 72 + 16 * ct + li] = f2bf(s[rt][ct][e] * rs);
      }
  }

  // ---- O = P V (64x32, K=64) ----
  f32x4 o[4][2];
  #pragma unroll
  for (int rt = 0; rt < 4; ++rt)
    #pragma unroll
    for (int ct = 0; ct < 2; ++ct) o[rt][ct] = f32x4{0.f, 0.f, 0.f, 0.f};
  #pragma unroll
  for (int ks = 0; ks < 2; ++ks) {
    bf16x8 pa[4], vb[2];
    #pragma unroll
    for (int rt = 0; rt < 4; ++rt)
      pa[rt] = *(const bf16x8*)(R + (16 * rt + li) * 72 + 32 * ks + 8 * g);
    #pragma unroll
    for (int ct = 0; ct < 2; ++ct)
      vb[ct] = *(const bf16x8*)(Vt + (32 * w + 16 * ct + li) * 72 + 32 * ks + 8 * g);
    #pragma unroll
    for (int rt = 0; rt < 4; ++rt)
      #pragma unroll
      for (int ct = 0; ct < 2; ++ct)
        o[rt][ct] = __builtin_amdgcn_mfma_f32_16x16x32_bf16(pa[rt], vb[ct], o[rt][ct], 0, 0, 0);
  }
  // attn_out bf16 -> R cols 0..31
  #pragma unroll
  for (int rt = 0; rt < 4; ++rt)
    #pragma unroll
    for (int ct = 0; ct < 2; ++ct)
      #pragma unroll
      for (int e = 0; e < 4; ++e)
        R[(16 * rt + 4 * g + e) * 72 + 16 * ct + li] = f2bf(o[rt][ct][e]);
  __syncthreads();

  // ---- proj: out = attn_out @ Wp^T + bp ; wave w -> cols 32w..32w+31 ----
  f32x4 c2[4][2];
  #pragma unroll
  for (int rt = 0; rt < 4; ++rt)
    #pragma unroll
    for (int ct = 0; ct < 2; ++ct) c2[rt][ct] = f32x4{0.f, 0.f, 0.f, 0.f};
  #pragma unroll
  for (int ks = 0; ks < 8; ++ks) {
    const u16* Rk = QK + ks * 4608;     // head ks attn_out, local cols 0..31
    bf16x8 a[4], bb[2];
    #pragma unroll
    for (int rt = 0; rt < 4; ++rt)
      a[rt] = *(const bf16x8*)(Rk + (16 * rt + li) * 72 + 8 * g);
    #pragma unroll
    for (int ct = 0; ct < 2; ++ct)
      bb[ct] = *(const bf16x8*)(wp + (32 * w + 16 * ct + li) * 256 + 32 * ks + 8 * g);
    #pragma unroll
    for (int rt = 0; rt < 4; ++rt)
      #pragma unroll
      for (int ct = 0; ct < 2; ++ct)
        c2[rt][ct] = __builtin_amdgcn_mfma_f32_16x16x32_bf16(a[rt], bb[ct], c2[rt][ct], 0, 0, 0);
  }
  {
    float* og = out + (size_t)b * 16384;
    #pragma unroll
    for (int ct = 0; ct < 2; ++ct) {
      int col = 32 * w + 16 * ct + li;
      float bpv = bp[col];
      #pragma unroll
      for (int rt = 0; rt < 4; ++rt)
        #pragma unroll
        for (int e = 0; e < 4; ++e)
          og[(16 * rt + 4 * g + e) * 256 + col] = c2[rt][ct][e] + bpv;
    }
  }
}

extern "C" void kernel_launch(void* const* d_in, const int* in_sizes, int n_in,
                              void* d_out, int out_size, void* d_ws, size_t ws_size,
                              hipStream_t stream) {
  const float* x   = (const float*)d_in[0];
  const float* wqv = (const float*)d_in[1];
  const float* bq  = (const float*)d_in[2];
  const float* wpr = (const float*)d_in[3];
  const float* bp  = (const float*)d_in[4];
  const float* rpb = (const float*)d_in[5];
  const int*   rpi = (const int*)d_in[6];
  float* out = (float*)d_out;

  u16*   wqb   = (u16*)d_ws;            // 196608 bf16
  u16*   wpb   = wqb + 196608;          // 65536 bf16
  float* biasb = (float*)(wpb + 65536); // 32768 f32

  wattn_prep<<<384, 512, 0, stream>>>(wqv, wpr, rpb, rpi, wqb, wpb, biasb);

  const size_t smem = (16896 + 36864 + 18432) * sizeof(u16);  // 144384 B
  hipFuncSetAttribute(reinterpret_cast<const void*>(wattn_main),
                      hipFuncAttributeMaxDynamicSharedMemorySize, (int)smem);
  wattn_main<<<8192, 512, smem, stream>>>(x, wqb, bq, wpb, bp, biasb, out);
}